// Round 4
// baseline (384.318 us; speedup 1.0000x reference)
//
#include <hip/hip_runtime.h>
#include <cstdint>

typedef unsigned long long ull;
typedef __bf16 bf16x8 __attribute__((ext_vector_type(8)));
typedef float f32x4 __attribute__((ext_vector_type(4)));

#define NPTS 8192
#define NB 2
#define KNN 16
#define DM 128
#define PADK 136

__device__ __forceinline__ float sq3f(float x, float y, float z) {
    return __fadd_rn(__fadd_rn(__fmul_rn(x, x), __fmul_rn(y, y)), __fmul_rn(z, z));
}
__device__ __forceinline__ float dot3f(float ax, float ay, float az, float bx, float by, float bz) {
    return __fadd_rn(__fadd_rn(__fmul_rn(ax, bx), __fmul_rn(ay, by)), __fmul_rn(az, bz));
}
__device__ __forceinline__ unsigned ford(float f) {
    unsigned u = __float_as_uint(f);
    return (u & 0x80000000u) ? ~u : (u | 0x80000000u);
}

// ---------------------------------------------------------------- KNN
// Wave-cooperative top-16 with float4-packed LDS candidates {x,y,z,sq}:
// one ds_read_b128 per candidate instead of 4 ds_read_b32 (R3 was LDS-pipe
// bound: VALUBusy 51%). Trigger test is a cheap u32 distance compare
// (conservative superset of key<thr); inserts use the full packed key, so
// selection stays bit-identical to jax.lax.top_k tie semantics.
__global__ __launch_bounds__(256) void knn_kernel(const float* __restrict__ xyz,
                                                  int* __restrict__ idx_out) {
    __shared__ float4 xs4[1024];
    const int t = threadIdx.x;
    const int wv = t >> 6, lane = t & 63;
    const int q_id = blockIdx.x * 4 + wv;
    const int b = q_id >> 13;
    const int i = q_id & (NPTS - 1);
    const float* xb = xyz + (size_t)b * NPTS * 3;
    const float qx = xb[3 * i + 0], qy = xb[3 * i + 1], qz = xb[3 * i + 2];
    const float sqi = sq3f(qx, qy, qz);

    ull list = ~0ull;           // lanes 0..15: sorted top-16 keys (ascending)
    unsigned thr_hi = 0xffffffffu;  // wave-uniform dist-bits of lane15's key

    for (int ch = 0; ch < 8; ++ch) {
        __syncthreads();
#pragma unroll
        for (int e = 0; e < 4; e++) {
            int p = t + e * 256;
            int g = ch * 1024 + p;
            float x = xb[3 * g + 0], y = xb[3 * g + 1], z = xb[3 * g + 2];
            xs4[p] = make_float4(x, y, z, sq3f(x, y, z));
        }
        __syncthreads();
#pragma unroll 4
        for (int m = 0; m < 16; m++) {
            int jl = m * 64 + lane;
            int j = ch * 1024 + jl;
            float4 P = xs4[jl];
            float d = __fsub_rn(__fadd_rn(sqi, P.w),
                                __fmul_rn(2.0f, dot3f(qx, qy, qz, P.x, P.y, P.z)));
            unsigned du = ford(d);
            ull ballot = __ballot(du <= thr_hi);   // conservative trigger
            if (ballot == 0ull) continue;          // wave-uniform branch
            ull key = ((ull)du << 32) | (unsigned)j;
            ull thr = (__shfl(list, 15));
            do {
                int l = __builtin_ctzll(ballot);
                ballot &= ballot - 1;
                ull ck = __shfl(key, l);
                if (ck >= thr) continue;           // equal-dist, larger idx: no-op
                // parallel insert into sorted lanes 0..15
                ull prev = __shfl_up(list, 1);
                bool shift = (ck < list);
                list = shift ? ((lane == 0 || ck >= prev) ? ck : prev) : list;
                thr = __shfl(list, 15);
            } while (ballot);
            thr_hi = (unsigned)(thr >> 32);
        }
    }
    if (lane < 16)
        idx_out[q_id * 16 + lane] = (int)(unsigned)(list & 0xffffffffu);
}

// ---------------------------------------------------------------- weight prep: f32 [k][n] -> bf16 [n][k]
__global__ __launch_bounds__(256) void wprep_kernel(const float* __restrict__ d2,
                                                    const float* __restrict__ g1,
                                                    const float* __restrict__ g2,
                                                    __bf16* __restrict__ d2t,
                                                    __bf16* __restrict__ g1t,
                                                    __bf16* __restrict__ g2t) {
    const float* src = (blockIdx.x == 0) ? d2 : ((blockIdx.x == 1) ? g1 : g2);
    __bf16* dst = (blockIdx.x == 0) ? d2t : ((blockIdx.x == 1) ? g1t : g2t);
#pragma unroll
    for (int e = 0; e < 64; e++) {
        int id = threadIdx.x + e * 256;
        int k = id >> 7, n = id & 127;
        dst[n * 128 + k] = (__bf16)src[id];
    }
}

// ---------------------------------------------------------------- x = features@fc1 + b
__global__ __launch_bounds__(256, 1) void gemm_x_kernel(const float* __restrict__ feats,
                                                        const float* __restrict__ w,
                                                        const float* __restrict__ bias,
                                                        float* __restrict__ xout) {
    __shared__ float At[64 * 65];
    __shared__ __align__(16) float Wt[64 * 128];
    const int t = threadIdx.x;
    const int base = blockIdx.x * 64;
#pragma unroll
    for (int e = 0; e < 16; e++) {
        int id = t + e * 256;
        int r = id >> 6, c = id & 63;
        At[c * 65 + r] = feats[(size_t)(base + r) * 64 + c];
    }
#pragma unroll
    for (int e = 0; e < 32; e++) { int id = t + e * 256; Wt[id] = w[id]; }
    __syncthreads();
    const int r0 = (t >> 4) * 4;
    const int c0 = (t & 15) * 8;
    float acc[4][8];
#pragma unroll
    for (int i = 0; i < 4; i++)
#pragma unroll
        for (int j = 0; j < 8; j++) acc[i][j] = bias[c0 + j];
#pragma unroll 4
    for (int kk = 0; kk < 64; ++kk) {
        float a0 = At[kk * 65 + r0 + 0];
        float a1 = At[kk * 65 + r0 + 1];
        float a2 = At[kk * 65 + r0 + 2];
        float a3 = At[kk * 65 + r0 + 3];
        const float4 w0 = *(const float4*)&Wt[kk * 128 + c0];
        const float4 w1 = *(const float4*)&Wt[kk * 128 + c0 + 4];
        float wj[8] = {w0.x, w0.y, w0.z, w0.w, w1.x, w1.y, w1.z, w1.w};
#pragma unroll
        for (int j = 0; j < 8; j++) {
            acc[0][j] += a0 * wj[j];
            acc[1][j] += a1 * wj[j];
            acc[2][j] += a2 * wj[j];
            acc[3][j] += a3 * wj[j];
        }
    }
#pragma unroll
    for (int i = 0; i < 4; i++)
#pragma unroll
        for (int j = 0; j < 8; j++)
            xout[(size_t)(base + r0 + i) * 128 + c0 + j] = acc[i][j];
}

// ---------------------------------------------------------------- q/xk/xv = x@W (no bias)
__global__ __launch_bounds__(256, 1) void gemm_qkv_kernel(const float* __restrict__ x,
                                                          const float* __restrict__ wq,
                                                          const float* __restrict__ wk,
                                                          const float* __restrict__ wv,
                                                          float* __restrict__ qo,
                                                          float* __restrict__ ko,
                                                          float* __restrict__ vo) {
    const float* w = (blockIdx.y == 0) ? wq : ((blockIdx.y == 1) ? wk : wv);
    float* o = (blockIdx.y == 0) ? qo : ((blockIdx.y == 1) ? ko : vo);
    __shared__ float At[128 * 65];
    __shared__ __align__(16) float Wt[128 * 128];
    const int t = threadIdx.x;
    const int base = blockIdx.x * 64;
#pragma unroll
    for (int e = 0; e < 32; e++) {
        int id = t + e * 256;
        int r = id >> 7, c = id & 127;
        At[c * 65 + r] = x[(size_t)(base + r) * 128 + c];
    }
#pragma unroll
    for (int e = 0; e < 64; e++) { int id = t + e * 256; Wt[id] = w[id]; }
    __syncthreads();
    const int r0 = (t >> 4) * 4;
    const int c0 = (t & 15) * 8;
    float acc[4][8];
#pragma unroll
    for (int i = 0; i < 4; i++)
#pragma unroll
        for (int j = 0; j < 8; j++) acc[i][j] = 0.0f;
#pragma unroll 4
    for (int kk = 0; kk < 128; ++kk) {
        float a0 = At[kk * 65 + r0 + 0];
        float a1 = At[kk * 65 + r0 + 1];
        float a2 = At[kk * 65 + r0 + 2];
        float a3 = At[kk * 65 + r0 + 3];
        const float4 w0 = *(const float4*)&Wt[kk * 128 + c0];
        const float4 w1 = *(const float4*)&Wt[kk * 128 + c0 + 4];
        float wj[8] = {w0.x, w0.y, w0.z, w0.w, w1.x, w1.y, w1.z, w1.w};
#pragma unroll
        for (int j = 0; j < 8; j++) {
            acc[0][j] += a0 * wj[j];
            acc[1][j] += a1 * wj[j];
            acc[2][j] += a2 * wj[j];
            acc[3][j] += a3 * wj[j];
        }
    }
#pragma unroll
    for (int i = 0; i < 4; i++)
#pragma unroll
        for (int j = 0; j < 8; j++)
            o[(size_t)(base + r0 + i) * 128 + c0 + j] = acc[i][j];
}

// MFMA K-loop over K=128: contiguous-8-per-lane fragments (m91/m92-verified convention)
#define DO_GEMM(ACC0, ACC1, WPTR)                                                          \
    {                                                                                      \
        _Pragma("unroll")                                                                  \
        for (int kt = 0; kt < 4; kt++) {                                                   \
            const int ko = kt * 32 + 8 * lg;                                               \
            bf16x8 a0 = *(const bf16x8*)&Ab[(rbase + lr) * PADK + ko];                     \
            bf16x8 a1 = *(const bf16x8*)&Ab[(rbase + 16 + lr) * PADK + ko];                \
            _Pragma("unroll")                                                              \
            for (int ct = 0; ct < 8; ct++) {                                               \
                bf16x8 bv = *(const bf16x8*)&WPTR[(ct * 16 + lr) * PADK + ko];             \
                ACC0[ct] = __builtin_amdgcn_mfma_f32_16x16x32_bf16(a0, bv, ACC0[ct], 0, 0, 0); \
                ACC1[ct] = __builtin_amdgcn_mfma_f32_16x16x32_bf16(a1, bv, ACC1[ct], 0, 0, 0); \
            }                                                                              \
        }                                                                                  \
    }

#define STAGE_W(SRC)                                                                       \
    {                                                                                      \
        _Pragma("unroll")                                                                  \
        for (int e = 0; e < 8; e++) {                                                      \
            int ch = t + e * 256;                                                          \
            int r = ch >> 4, ck = ch & 15;                                                 \
            *(bf16x8*)&Wb[r * PADK + ck * 8] = *(const bf16x8*)&SRC[r * 128 + ck * 8];     \
        }                                                                                  \
    }

// ---------------------------------------------------------------- fused k3+k4
__global__ __launch_bounds__(256, 2) void k34_kernel(const float* __restrict__ xyz,
                                                     const int* __restrict__ idxw,
                                                     const float* __restrict__ q,
                                                     const float* __restrict__ xk,
                                                     const float* __restrict__ d1,
                                                     const float* __restrict__ bd1,
                                                     const float* __restrict__ bd2,
                                                     const float* __restrict__ bg1,
                                                     const float* __restrict__ bg2,
                                                     const __bf16* __restrict__ d2t,
                                                     const __bf16* __restrict__ g1t,
                                                     const __bf16* __restrict__ g2t,
                                                     float* __restrict__ attn) {
    __shared__ __bf16 Ab[128 * PADK];
    __shared__ __bf16 Wb[128 * PADK];
    __shared__ float rels[128 * 4];
    __shared__ int jrow[128];
    __shared__ float d1s[3 * 128];
    __shared__ float bd1s[128], bd2s[128], bg1s[128], bg2s[128];

    const int t = threadIdx.x;
    const int wv = t >> 6;
    const int lane = t & 63;
    const int lr = lane & 15, lg = lane >> 4;
    const int R0 = blockIdx.x * 128;
    const int b = R0 >> 17;
    const int rbase = wv * 32;

#pragma unroll
    for (int e = 0; e < 2; e++) { int id = t + e * 256; if (id < 384) d1s[id] = d1[id]; }
    if (t < 128) {
        bd1s[t] = bd1[t]; bd2s[t] = bd2[t]; bg1s[t] = bg1[t]; bg2s[t] = bg2[t];
    } else {
        int r = t - 128;
        int j = idxw[R0 + r];
        jrow[r] = j;
        const float* pn = xyz + (size_t)((R0 + r) >> 4) * 3;
        const float* pj = xyz + (size_t)((b << 13) + j) * 3;
        rels[r * 4 + 0] = pn[0] - pj[0];
        rels[r * 4 + 1] = pn[1] - pj[1];
        rels[r * 4 + 2] = pn[2] - pj[2];
    }
    STAGE_W(d2t)
    __syncthreads();

    // T = relu(rel@d1 + bd1) -> Ab (bf16)
    {
        const int c = t & 127;
        const float w0 = d1s[c], w1 = d1s[128 + c], w2 = d1s[256 + c], bb = bd1s[c];
#pragma unroll
        for (int e = 0; e < 64; e++) {
            int r = (t >> 7) + e * 2;
            float v = fmaf(rels[r * 4 + 2], w2,
                      fmaf(rels[r * 4 + 1], w1, fmaf(rels[r * 4 + 0], w0, bb)));
            Ab[r * PADK + c] = (__bf16)fmaxf(v, 0.0f);
        }
    }
    __syncthreads();

    // GEMM1: pos = T@d2 + bd2
    f32x4 acc0[8], acc1[8];
#pragma unroll
    for (int ct = 0; ct < 8; ct++) {
        float bb = bd2s[ct * 16 + lr];
        acc0[ct] = (f32x4){bb, bb, bb, bb};
        acc1[ct] = acc0[ct];
    }
    DO_GEMM(acc0, acc1, Wb)

    // h = relu(pos) + q - k_nbr  -> Ab (bf16)
#pragma unroll
    for (int rt = 0; rt < 2; rt++) {
        const int rloc = rbase + rt * 16 + 4 * lg;
        const size_t qbase = (size_t)((R0 + rloc) >> 4) * 128;
        const int j0 = jrow[rloc + 0], j1 = jrow[rloc + 1];
        const int j2 = jrow[rloc + 2], j3 = jrow[rloc + 3];
        const size_t kb0 = (size_t)((b << 13) + j0) * 128;
        const size_t kb1 = (size_t)((b << 13) + j1) * 128;
        const size_t kb2 = (size_t)((b << 13) + j2) * 128;
        const size_t kb3 = (size_t)((b << 13) + j3) * 128;
        f32x4* accR = rt ? acc1 : acc0;
#pragma unroll
        for (int ct = 0; ct < 8; ct++) {
            const int c = ct * 16 + lr;
            const float qv = q[qbase + c];
            f32x4 p = accR[ct];
            Ab[(rloc + 0) * PADK + c] = (__bf16)(fmaxf(p[0], 0.0f) + qv - xk[kb0 + c]);
            Ab[(rloc + 1) * PADK + c] = (__bf16)(fmaxf(p[1], 0.0f) + qv - xk[kb1 + c]);
            Ab[(rloc + 2) * PADK + c] = (__bf16)(fmaxf(p[2], 0.0f) + qv - xk[kb2 + c]);
            Ab[(rloc + 3) * PADK + c] = (__bf16)(fmaxf(p[3], 0.0f) + qv - xk[kb3 + c]);
        }
    }
    __syncthreads();
    STAGE_W(g1t)
    __syncthreads();

    // GEMM2: u = relu(h@g1 + bg1) -> Ab (bf16)
#pragma unroll
    for (int ct = 0; ct < 8; ct++) {
        float bb = bg1s[ct * 16 + lr];
        acc0[ct] = (f32x4){bb, bb, bb, bb};
        acc1[ct] = acc0[ct];
    }
    DO_GEMM(acc0, acc1, Wb)
#pragma unroll
    for (int rt = 0; rt < 2; rt++) {
        const int rloc = rbase + rt * 16 + 4 * lg;
        f32x4* accR = rt ? acc1 : acc0;
#pragma unroll
        for (int ct = 0; ct < 8; ct++) {
            const int c = ct * 16 + lr;
            f32x4 p = accR[ct];
            Ab[(rloc + 0) * PADK + c] = (__bf16)fmaxf(p[0], 0.0f);
            Ab[(rloc + 1) * PADK + c] = (__bf16)fmaxf(p[1], 0.0f);
            Ab[(rloc + 2) * PADK + c] = (__bf16)fmaxf(p[2], 0.0f);
            Ab[(rloc + 3) * PADK + c] = (__bf16)fmaxf(p[3], 0.0f);
        }
    }
    __syncthreads();
    STAGE_W(g2t)
    __syncthreads();

    // GEMM3: logits = u@g2 + bg2 ; softmax over 16 neighbors ; write attn
#pragma unroll
    for (int ct = 0; ct < 8; ct++) {
        float bb = bg2s[ct * 16 + lr];
        acc0[ct] = (f32x4){bb, bb, bb, bb};
        acc1[ct] = acc0[ct];
    }
    DO_GEMM(acc0, acc1, Wb)
    const float scale = 0.08838834764831845f; /* 1/sqrt(128) */
#pragma unroll
    for (int rt = 0; rt < 2; rt++) {
        const int rloc = rbase + rt * 16 + 4 * lg;
        f32x4* accR = rt ? acc1 : acc0;
#pragma unroll
        for (int ct = 0; ct < 8; ct++) {
            const int c = ct * 16 + lr;
            f32x4 p = accR[ct];
            float l0 = p[0] * scale, l1 = p[1] * scale, l2 = p[2] * scale, l3 = p[3] * scale;
            float m = fmaxf(fmaxf(l0, l1), fmaxf(l2, l3));
            m = fmaxf(m, __shfl_xor(m, 16));
            m = fmaxf(m, __shfl_xor(m, 32));
            float e0 = __expf(l0 - m), e1 = __expf(l1 - m);
            float e2 = __expf(l2 - m), e3 = __expf(l3 - m);
            float s = (e0 + e1) + (e2 + e3);
            s += __shfl_xor(s, 16);
            s += __shfl_xor(s, 32);
            float inv = 1.0f / s;
            size_t ob = (size_t)(R0 + rloc) * 128 + c;
            attn[ob + 0 * 128] = e0 * inv;
            attn[ob + 1 * 128] = e1 * inv;
            attn[ob + 2 * 128] = e2 * inv;
            attn[ob + 3 * 128] = e3 * inv;
        }
    }
}

// ---------------------------------------------------------------- k5: pos (MFMA) + res_pre = sum_k attn*(v+pos)
__global__ __launch_bounds__(256, 2) void k5_kernel(const float* __restrict__ xyz,
                                                    const int* __restrict__ idxw,
                                                    const float* __restrict__ xv,
                                                    const float* __restrict__ d1,
                                                    const float* __restrict__ bd1,
                                                    const float* __restrict__ bd2,
                                                    const __bf16* __restrict__ d2t,
                                                    const float* __restrict__ attn,
                                                    float* __restrict__ res_pre) {
    __shared__ __bf16 Ab[128 * PADK];
    __shared__ __bf16 Wb[128 * PADK];
    __shared__ float rels[128 * 4];
    __shared__ int jrow[128];
    __shared__ float d1s[3 * 128];
    __shared__ float bd1s[128], bd2s[128];

    const int t = threadIdx.x;
    const int wv = t >> 6;
    const int lane = t & 63;
    const int lr = lane & 15, lg = lane >> 4;
    const int R0 = blockIdx.x * 128;
    const int b = R0 >> 17;
    const int rbase = wv * 32;

#pragma unroll
    for (int e = 0; e < 2; e++) { int id = t + e * 256; if (id < 384) d1s[id] = d1[id]; }
    if (t < 128) {
        bd1s[t] = bd1[t]; bd2s[t] = bd2[t];
    } else {
        int r = t - 128;
        int j = idxw[R0 + r];
        jrow[r] = j;
        const float* pn = xyz + (size_t)((R0 + r) >> 4) * 3;
        const float* pj = xyz + (size_t)((b << 13) + j) * 3;
        rels[r * 4 + 0] = pn[0] - pj[0];
        rels[r * 4 + 1] = pn[1] - pj[1];
        rels[r * 4 + 2] = pn[2] - pj[2];
    }
    STAGE_W(d2t)
    __syncthreads();

    {
        const int c = t & 127;
        const float w0 = d1s[c], w1 = d1s[128 + c], w2 = d1s[256 + c], bb = bd1s[c];
#pragma unroll
        for (int e = 0; e < 64; e++) {
            int r = (t >> 7) + e * 2;
            float v = fmaf(rels[r * 4 + 2], w2,
                      fmaf(rels[r * 4 + 1], w1, fmaf(rels[r * 4 + 0], w0, bb)));
            Ab[r * PADK + c] = (__bf16)fmaxf(v, 0.0f);
        }
    }
    __syncthreads();

    f32x4 acc0[8], acc1[8];
#pragma unroll
    for (int ct = 0; ct < 8; ct++) {
        float bb = bd2s[ct * 16 + lr];
        acc0[ct] = (f32x4){bb, bb, bb, bb};
        acc1[ct] = acc0[ct];
    }
    DO_GEMM(acc0, acc1, Wb)

#pragma unroll
    for (int rt = 0; rt < 2; rt++) {
        const int rloc = rbase + rt * 16 + 4 * lg;
        const int j0 = jrow[rloc + 0], j1 = jrow[rloc + 1];
        const int j2 = jrow[rloc + 2], j3 = jrow[rloc + 3];
        const size_t vb0 = (size_t)((b << 13) + j0) * 128;
        const size_t vb1 = (size_t)((b << 13) + j1) * 128;
        const size_t vb2 = (size_t)((b << 13) + j2) * 128;
        const size_t vb3 = (size_t)((b << 13) + j3) * 128;
        const size_t ab = (size_t)(R0 + rloc) * 128;
        f32x4* accR = rt ? acc1 : acc0;
#pragma unroll
        for (int ct = 0; ct < 8; ct++) {
            const int c = ct * 16 + lr;
            f32x4 p = accR[ct];
            float s = attn[ab + 0 * 128 + c] * (xv[vb0 + c] + fmaxf(p[0], 0.0f))
                    + attn[ab + 1 * 128 + c] * (xv[vb1 + c] + fmaxf(p[1], 0.0f))
                    + attn[ab + 2 * 128 + c] * (xv[vb2 + c] + fmaxf(p[2], 0.0f))
                    + attn[ab + 3 * 128 + c] * (xv[vb3 + c] + fmaxf(p[3], 0.0f));
            s += __shfl_xor(s, 16);
            s += __shfl_xor(s, 32);
            if (lg == 0)
                res_pre[(size_t)((R0 >> 4) + wv * 2 + rt) * 128 + c] = s;
        }
    }
}

// ---------------------------------------------------------------- res = res_pre@fc2 + b + features
__global__ __launch_bounds__(256, 1) void k6_kernel(const float* __restrict__ res_pre,
                                                    const float* __restrict__ w,
                                                    const float* __restrict__ bias,
                                                    const float* __restrict__ feats,
                                                    float* __restrict__ res_out) {
    __shared__ float At[128 * 65];
    __shared__ __align__(16) float Wt[128 * 64];
    const int t = threadIdx.x;
    const int base = blockIdx.x * 64;
#pragma unroll
    for (int e = 0; e < 32; e++) {
        int id = t + e * 256;
        int r = id >> 7, c = id & 127;
        At[c * 65 + r] = res_pre[(size_t)(base + r) * 128 + c];
    }
#pragma unroll
    for (int e = 0; e < 32; e++) { int id = t + e * 256; Wt[id] = w[id]; }
    __syncthreads();
    const int r0 = (t >> 4) * 4;
    const int c0 = (t & 15) * 4;
    float acc[4][4];
#pragma unroll
    for (int i = 0; i < 4; i++)
#pragma unroll
        for (int j = 0; j < 4; j++) acc[i][j] = bias[c0 + j];
#pragma unroll 4
    for (int kk = 0; kk < 128; ++kk) {
        float a0 = At[kk * 65 + r0 + 0];
        float a1 = At[kk * 65 + r0 + 1];
        float a2 = At[kk * 65 + r0 + 2];
        float a3 = At[kk * 65 + r0 + 3];
        const float4 w0 = *(const float4*)&Wt[kk * 64 + c0];
        float wj[4] = {w0.x, w0.y, w0.z, w0.w};
#pragma unroll
        for (int j = 0; j < 4; j++) {
            acc[0][j] += a0 * wj[j];
            acc[1][j] += a1 * wj[j];
            acc[2][j] += a2 * wj[j];
            acc[3][j] += a3 * wj[j];
        }
    }
#pragma unroll
    for (int i = 0; i < 4; i++)
#pragma unroll
        for (int j = 0; j < 4; j++)
            res_out[(size_t)(base + r0 + i) * 64 + c0 + j] =
                acc[i][j] + feats[(size_t)(base + r0 + i) * 64 + c0 + j];
}

extern "C" void kernel_launch(void* const* d_in, const int* in_sizes, int n_in,
                              void* d_out, int out_size, void* d_ws, size_t ws_size,
                              hipStream_t stream) {
    (void)in_sizes; (void)n_in; (void)out_size; (void)ws_size;
    const float* xyz   = (const float*)d_in[0];
    const float* feats = (const float*)d_in[2];
    const float* fc1_w = (const float*)d_in[3];
    const float* fc1_b = (const float*)d_in[4];
    const float* fc2_w = (const float*)d_in[5];
    const float* fc2_b = (const float*)d_in[6];
    const float* g1    = (const float*)d_in[7];
    const float* bg1   = (const float*)d_in[8];
    const float* g2    = (const float*)d_in[9];
    const float* bg2   = (const float*)d_in[10];
    const float* d1    = (const float*)d_in[11];
    const float* bd1   = (const float*)d_in[12];
    const float* d2    = (const float*)d_in[13];
    const float* bd2   = (const float*)d_in[14];
    const float* wq    = (const float*)d_in[15];
    const float* wk    = (const float*)d_in[16];
    const float* wv    = (const float*)d_in[17];

    int* idxw   = (int*)d_ws;
    float* xbuf = (float*)((char*)d_ws + (1 << 20));
    float* qbuf = xbuf + 2097152;
    float* kbuf = qbuf + 2097152;
    float* vbuf = kbuf + 2097152;
    float* rpre = vbuf + 2097152;
    __bf16* d2t = (__bf16*)(rpre + 2097152);
    __bf16* g1t = d2t + 16384;
    __bf16* g2t = g1t + 16384;

    float* res_out = (float*)d_out;
    float* attn    = res_out + 1048576;

    wprep_kernel<<<3, 256, 0, stream>>>(d2, g1, g2, d2t, g1t, g2t);
    knn_kernel<<<4096, 256, 0, stream>>>(xyz, idxw);
    gemm_x_kernel<<<256, 256, 0, stream>>>(feats, fc1_w, fc1_b, xbuf);
    gemm_qkv_kernel<<<dim3(256, 3), 256, 0, stream>>>(xbuf, wq, wk, wv, qbuf, kbuf, vbuf);
    k34_kernel<<<2048, 256, 0, stream>>>(xyz, idxw, qbuf, kbuf, d1, bd1, bd2, bg1, bg2,
                                         d2t, g1t, g2t, attn);
    k5_kernel<<<2048, 256, 0, stream>>>(xyz, idxw, vbuf, d1, bd1, bd2, d2t, attn, rpre);
    k6_kernel<<<256, 256, 0, stream>>>(rpre, fc2_w, fc2_b, feats, res_out);
}

// Round 5
// 288.851 us; speedup vs baseline: 1.3305x; 1.3305x over previous
//
#include <hip/hip_runtime.h>
#include <cstdint>

typedef unsigned long long ull;
typedef __bf16 bf16x8 __attribute__((ext_vector_type(8)));
typedef float f32x4 __attribute__((ext_vector_type(4)));

#define NPTS 8192
#define NB 2
#define KNN 16
#define DM 128
#define PADK 136

__device__ __forceinline__ float sq3f(float x, float y, float z) {
    return __fadd_rn(__fadd_rn(__fmul_rn(x, x), __fmul_rn(y, y)), __fmul_rn(z, z));
}
__device__ __forceinline__ float dot3f(float ax, float ay, float az, float bx, float by, float bz) {
    return __fadd_rn(__fadd_rn(__fmul_rn(ax, bx), __fmul_rn(ay, by)), __fmul_rn(az, bz));
}
__device__ __forceinline__ unsigned ford(float f) {
    unsigned u = __float_as_uint(f);
    return (u & 0x80000000u) ? ~u : (u | 0x80000000u);
}

// ---------------------------------------------------------------- KNN
// Wave-cooperative top-16. R4 lesson: __shfl = ds_bpermute shares the LDS
// pipe and the ~116 inserts/query at ~6 bperms each were the bottleneck.
// Now: candidate broadcast via v_readlane (VALU pipe), index half computed
// scalarly (affine in lane), thr refresh via readlane. Only the 64-bit
// shfl_up shift (2 ds ops) remains per insert. Selection bit-identical to
// jax.lax.top_k (lexicographic (dist_bits, idx), lower idx wins ties).
__global__ __launch_bounds__(256) void knn_kernel(const float* __restrict__ xyz,
                                                  int* __restrict__ idx_out) {
    __shared__ float4 xs4[1024];
    const int t = threadIdx.x;
    const int wv = t >> 6, lane = t & 63;
    const int q_id = blockIdx.x * 4 + wv;
    const int b = q_id >> 13;
    const int i = q_id & (NPTS - 1);
    const float* xb = xyz + (size_t)b * NPTS * 3;
    const float qx = xb[3 * i + 0], qy = xb[3 * i + 1], qz = xb[3 * i + 2];
    const float sqi = sq3f(qx, qy, qz);

    // lanes 0..15: sorted top-16 (ascending, lexicographic (hi,lo))
    unsigned list_hi = 0xffffffffu, list_lo = 0xffffffffu;
    unsigned thr_hi = 0xffffffffu, thr_lo = 0xffffffffu;  // wave-uniform copy of lane15

    for (int ch = 0; ch < 8; ++ch) {
        __syncthreads();
#pragma unroll
        for (int e = 0; e < 4; e++) {
            int p = t + e * 256;
            int g = ch * 1024 + p;
            float x = xb[3 * g + 0], y = xb[3 * g + 1], z = xb[3 * g + 2];
            xs4[p] = make_float4(x, y, z, sq3f(x, y, z));
        }
        __syncthreads();
#pragma unroll 4
        for (int m = 0; m < 16; m++) {
            int jl = m * 64 + lane;
            float4 P = xs4[jl];
            float d = __fsub_rn(__fadd_rn(sqi, P.w),
                                __fmul_rn(2.0f, dot3f(qx, qy, qz, P.x, P.y, P.z)));
            unsigned du = ford(d);
            unsigned jme = (unsigned)(ch * 1024 + jl);
            bool trig = (du < thr_hi) || (du == thr_hi && jme < thr_lo);
            ull ballot = __ballot(trig);
            if (ballot == 0ull) continue;       // wave-uniform branch
            const unsigned jbase = (unsigned)(ch * 1024 + m * 64);
            do {
                int l = (int)__builtin_ctzll(ballot);
                ballot &= ballot - 1;
                unsigned ck_hi = (unsigned)__builtin_amdgcn_readlane((int)du, l); // VALU, not DS
                unsigned ck_lo = jbase + (unsigned)l;                              // scalar!
                // parallel insert into sorted lanes 0..15 (stale-thr entries are no-ops)
                unsigned ph = __shfl_up(list_hi, 1);
                unsigned pl = __shfl_up(list_lo, 1);
                bool ck_lt_list = (ck_hi < list_hi) || (ck_hi == list_hi && ck_lo < list_lo);
                bool ck_ge_prev = (lane == 0) || (ck_hi > ph) || (ck_hi == ph && ck_lo >= pl);
                unsigned nh = ck_ge_prev ? ck_hi : ph;
                unsigned nl = ck_ge_prev ? ck_lo : pl;
                list_hi = ck_lt_list ? nh : list_hi;
                list_lo = ck_lt_list ? nl : list_lo;
            } while (ballot);
            thr_hi = (unsigned)__builtin_amdgcn_readlane((int)list_hi, 15);  // VALU, not DS
            thr_lo = (unsigned)__builtin_amdgcn_readlane((int)list_lo, 15);
        }
    }
    if (lane < 16)
        idx_out[q_id * 16 + lane] = (int)list_lo;
}

// ---------------------------------------------------------------- weight prep: f32 [k][n] -> bf16 [n][k]
__global__ __launch_bounds__(256) void wprep_kernel(const float* __restrict__ d2,
                                                    const float* __restrict__ g1,
                                                    const float* __restrict__ g2,
                                                    __bf16* __restrict__ d2t,
                                                    __bf16* __restrict__ g1t,
                                                    __bf16* __restrict__ g2t) {
    const float* src = (blockIdx.x == 0) ? d2 : ((blockIdx.x == 1) ? g1 : g2);
    __bf16* dst = (blockIdx.x == 0) ? d2t : ((blockIdx.x == 1) ? g1t : g2t);
#pragma unroll
    for (int e = 0; e < 64; e++) {
        int id = threadIdx.x + e * 256;
        int k = id >> 7, n = id & 127;
        dst[n * 128 + k] = (__bf16)src[id];
    }
}

// ---------------------------------------------------------------- x = features@fc1 + b
__global__ __launch_bounds__(256, 1) void gemm_x_kernel(const float* __restrict__ feats,
                                                        const float* __restrict__ w,
                                                        const float* __restrict__ bias,
                                                        float* __restrict__ xout) {
    __shared__ float At[64 * 65];
    __shared__ __align__(16) float Wt[64 * 128];
    const int t = threadIdx.x;
    const int base = blockIdx.x * 64;
#pragma unroll
    for (int e = 0; e < 16; e++) {
        int id = t + e * 256;
        int r = id >> 6, c = id & 63;
        At[c * 65 + r] = feats[(size_t)(base + r) * 64 + c];
    }
#pragma unroll
    for (int e = 0; e < 32; e++) { int id = t + e * 256; Wt[id] = w[id]; }
    __syncthreads();
    const int r0 = (t >> 4) * 4;
    const int c0 = (t & 15) * 8;
    float acc[4][8];
#pragma unroll
    for (int i = 0; i < 4; i++)
#pragma unroll
        for (int j = 0; j < 8; j++) acc[i][j] = bias[c0 + j];
#pragma unroll 4
    for (int kk = 0; kk < 64; ++kk) {
        float a0 = At[kk * 65 + r0 + 0];
        float a1 = At[kk * 65 + r0 + 1];
        float a2 = At[kk * 65 + r0 + 2];
        float a3 = At[kk * 65 + r0 + 3];
        const float4 w0 = *(const float4*)&Wt[kk * 128 + c0];
        const float4 w1 = *(const float4*)&Wt[kk * 128 + c0 + 4];
        float wj[8] = {w0.x, w0.y, w0.z, w0.w, w1.x, w1.y, w1.z, w1.w};
#pragma unroll
        for (int j = 0; j < 8; j++) {
            acc[0][j] += a0 * wj[j];
            acc[1][j] += a1 * wj[j];
            acc[2][j] += a2 * wj[j];
            acc[3][j] += a3 * wj[j];
        }
    }
#pragma unroll
    for (int i = 0; i < 4; i++)
#pragma unroll
        for (int j = 0; j < 8; j++)
            xout[(size_t)(base + r0 + i) * 128 + c0 + j] = acc[i][j];
}

// ---------------------------------------------------------------- q/xk/xv = x@W (no bias)
__global__ __launch_bounds__(256, 1) void gemm_qkv_kernel(const float* __restrict__ x,
                                                          const float* __restrict__ wq,
                                                          const float* __restrict__ wk,
                                                          const float* __restrict__ wv,
                                                          float* __restrict__ qo,
                                                          float* __restrict__ ko,
                                                          float* __restrict__ vo) {
    const float* w = (blockIdx.y == 0) ? wq : ((blockIdx.y == 1) ? wk : wv);
    float* o = (blockIdx.y == 0) ? qo : ((blockIdx.y == 1) ? ko : vo);
    __shared__ float At[128 * 65];
    __shared__ __align__(16) float Wt[128 * 128];
    const int t = threadIdx.x;
    const int base = blockIdx.x * 64;
#pragma unroll
    for (int e = 0; e < 32; e++) {
        int id = t + e * 256;
        int r = id >> 7, c = id & 127;
        At[c * 65 + r] = x[(size_t)(base + r) * 128 + c];
    }
#pragma unroll
    for (int e = 0; e < 64; e++) { int id = t + e * 256; Wt[id] = w[id]; }
    __syncthreads();
    const int r0 = (t >> 4) * 4;
    const int c0 = (t & 15) * 8;
    float acc[4][8];
#pragma unroll
    for (int i = 0; i < 4; i++)
#pragma unroll
        for (int j = 0; j < 8; j++) acc[i][j] = 0.0f;
#pragma unroll 4
    for (int kk = 0; kk < 128; ++kk) {
        float a0 = At[kk * 65 + r0 + 0];
        float a1 = At[kk * 65 + r0 + 1];
        float a2 = At[kk * 65 + r0 + 2];
        float a3 = At[kk * 65 + r0 + 3];
        const float4 w0 = *(const float4*)&Wt[kk * 128 + c0];
        const float4 w1 = *(const float4*)&Wt[kk * 128 + c0 + 4];
        float wj[8] = {w0.x, w0.y, w0.z, w0.w, w1.x, w1.y, w1.z, w1.w};
#pragma unroll
        for (int j = 0; j < 8; j++) {
            acc[0][j] += a0 * wj[j];
            acc[1][j] += a1 * wj[j];
            acc[2][j] += a2 * wj[j];
            acc[3][j] += a3 * wj[j];
        }
    }
#pragma unroll
    for (int i = 0; i < 4; i++)
#pragma unroll
        for (int j = 0; j < 8; j++)
            o[(size_t)(base + r0 + i) * 128 + c0 + j] = acc[i][j];
}

// MFMA K-loop over K=128: contiguous-8-per-lane fragments (m91/m92-verified convention)
#define DO_GEMM(ACC0, ACC1, WPTR)                                                          \
    {                                                                                      \
        _Pragma("unroll")                                                                  \
        for (int kt = 0; kt < 4; kt++) {                                                   \
            const int ko = kt * 32 + 8 * lg;                                               \
            bf16x8 a0 = *(const bf16x8*)&Ab[(rbase + lr) * PADK + ko];                     \
            bf16x8 a1 = *(const bf16x8*)&Ab[(rbase + 16 + lr) * PADK + ko];                \
            _Pragma("unroll")                                                              \
            for (int ct = 0; ct < 8; ct++) {                                               \
                bf16x8 bv = *(const bf16x8*)&WPTR[(ct * 16 + lr) * PADK + ko];             \
                ACC0[ct] = __builtin_amdgcn_mfma_f32_16x16x32_bf16(a0, bv, ACC0[ct], 0, 0, 0); \
                ACC1[ct] = __builtin_amdgcn_mfma_f32_16x16x32_bf16(a1, bv, ACC1[ct], 0, 0, 0); \
            }                                                                              \
        }                                                                                  \
    }

#define STAGE_W(SRC)                                                                       \
    {                                                                                      \
        _Pragma("unroll")                                                                  \
        for (int e = 0; e < 8; e++) {                                                      \
            int ch = t + e * 256;                                                          \
            int r = ch >> 4, ck = ch & 15;                                                 \
            *(bf16x8*)&Wb[r * PADK + ck * 8] = *(const bf16x8*)&SRC[r * 128 + ck * 8];     \
        }                                                                                  \
    }

// ---------------------------------------------------------------- fused k3+k4+k5:
// pos -> h -> u -> logits -> softmax -> attn  AND  res_pre = sum_k attn*(v+pos)
// (pos kept in registers across GEMM2/3; k5's duplicate pos-MFMA + attn
// re-read eliminated)
__global__ __launch_bounds__(256, 2) void k345_kernel(const float* __restrict__ xyz,
                                                      const int* __restrict__ idxw,
                                                      const float* __restrict__ q,
                                                      const float* __restrict__ xk,
                                                      const float* __restrict__ xv,
                                                      const float* __restrict__ d1,
                                                      const float* __restrict__ bd1,
                                                      const float* __restrict__ bd2,
                                                      const float* __restrict__ bg1,
                                                      const float* __restrict__ bg2,
                                                      const __bf16* __restrict__ d2t,
                                                      const __bf16* __restrict__ g1t,
                                                      const __bf16* __restrict__ g2t,
                                                      float* __restrict__ attn,
                                                      float* __restrict__ res_pre) {
    __shared__ __bf16 Ab[128 * PADK];
    __shared__ __bf16 Wb[128 * PADK];
    __shared__ float rels[128 * 4];
    __shared__ int jrow[128];
    __shared__ float d1s[3 * 128];
    __shared__ float bd1s[128], bd2s[128], bg1s[128], bg2s[128];

    const int t = threadIdx.x;
    const int wv = t >> 6;
    const int lane = t & 63;
    const int lr = lane & 15, lg = lane >> 4;
    const int R0 = blockIdx.x * 128;
    const int b = R0 >> 17;
    const int rbase = wv * 32;

#pragma unroll
    for (int e = 0; e < 2; e++) { int id = t + e * 256; if (id < 384) d1s[id] = d1[id]; }
    if (t < 128) {
        bd1s[t] = bd1[t]; bd2s[t] = bd2[t]; bg1s[t] = bg1[t]; bg2s[t] = bg2[t];
    } else {
        int r = t - 128;
        int j = idxw[R0 + r];
        jrow[r] = j;
        const float* pn = xyz + (size_t)((R0 + r) >> 4) * 3;
        const float* pj = xyz + (size_t)((b << 13) + j) * 3;
        rels[r * 4 + 0] = pn[0] - pj[0];
        rels[r * 4 + 1] = pn[1] - pj[1];
        rels[r * 4 + 2] = pn[2] - pj[2];
    }
    STAGE_W(d2t)
    __syncthreads();

    // T = relu(rel@d1 + bd1) -> Ab (bf16)
    {
        const int c = t & 127;
        const float w0 = d1s[c], w1 = d1s[128 + c], w2 = d1s[256 + c], bb = bd1s[c];
#pragma unroll
        for (int e = 0; e < 64; e++) {
            int r = (t >> 7) + e * 2;
            float v = fmaf(rels[r * 4 + 2], w2,
                      fmaf(rels[r * 4 + 1], w1, fmaf(rels[r * 4 + 0], w0, bb)));
            Ab[r * PADK + c] = (__bf16)fmaxf(v, 0.0f);
        }
    }
    __syncthreads();

    // GEMM1: pos = relu(T@d2 + bd2), kept in registers for h AND the value path
    f32x4 acc0[8], acc1[8];
#pragma unroll
    for (int ct = 0; ct < 8; ct++) {
        float bb = bd2s[ct * 16 + lr];
        acc0[ct] = (f32x4){bb, bb, bb, bb};
        acc1[ct] = acc0[ct];
    }
    DO_GEMM(acc0, acc1, Wb)
    f32x4 pos0[8], pos1[8];
#pragma unroll
    for (int ct = 0; ct < 8; ct++) {
#pragma unroll
        for (int e = 0; e < 4; e++) {
            pos0[ct][e] = fmaxf(acc0[ct][e], 0.0f);
            pos1[ct][e] = fmaxf(acc1[ct][e], 0.0f);
        }
    }

    // h = pos + q - k_nbr  -> Ab (bf16)   [own rows only]
#pragma unroll
    for (int rt = 0; rt < 2; rt++) {
        const int rloc = rbase + rt * 16 + 4 * lg;
        const size_t qbase = (size_t)((R0 + rloc) >> 4) * 128;
        const int j0 = jrow[rloc + 0], j1 = jrow[rloc + 1];
        const int j2 = jrow[rloc + 2], j3 = jrow[rloc + 3];
        const size_t kb0 = (size_t)((b << 13) + j0) * 128;
        const size_t kb1 = (size_t)((b << 13) + j1) * 128;
        const size_t kb2 = (size_t)((b << 13) + j2) * 128;
        const size_t kb3 = (size_t)((b << 13) + j3) * 128;
        f32x4* posR = rt ? pos1 : pos0;
#pragma unroll
        for (int ct = 0; ct < 8; ct++) {
            const int c = ct * 16 + lr;
            const float qv = q[qbase + c];
            f32x4 p = posR[ct];
            Ab[(rloc + 0) * PADK + c] = (__bf16)(p[0] + qv - xk[kb0 + c]);
            Ab[(rloc + 1) * PADK + c] = (__bf16)(p[1] + qv - xk[kb1 + c]);
            Ab[(rloc + 2) * PADK + c] = (__bf16)(p[2] + qv - xk[kb2 + c]);
            Ab[(rloc + 3) * PADK + c] = (__bf16)(p[3] + qv - xk[kb3 + c]);
        }
    }
    __syncthreads();
    STAGE_W(g1t)
    __syncthreads();

    // GEMM2: u = relu(h@g1 + bg1) -> Ab (bf16)
#pragma unroll
    for (int ct = 0; ct < 8; ct++) {
        float bb = bg1s[ct * 16 + lr];
        acc0[ct] = (f32x4){bb, bb, bb, bb};
        acc1[ct] = acc0[ct];
    }
    DO_GEMM(acc0, acc1, Wb)
#pragma unroll
    for (int rt = 0; rt < 2; rt++) {
        const int rloc = rbase + rt * 16 + 4 * lg;
        f32x4* accR = rt ? acc1 : acc0;
#pragma unroll
        for (int ct = 0; ct < 8; ct++) {
            const int c = ct * 16 + lr;
            f32x4 p = accR[ct];
            Ab[(rloc + 0) * PADK + c] = (__bf16)fmaxf(p[0], 0.0f);
            Ab[(rloc + 1) * PADK + c] = (__bf16)fmaxf(p[1], 0.0f);
            Ab[(rloc + 2) * PADK + c] = (__bf16)fmaxf(p[2], 0.0f);
            Ab[(rloc + 3) * PADK + c] = (__bf16)fmaxf(p[3], 0.0f);
        }
    }
    __syncthreads();
    STAGE_W(g2t)
    __syncthreads();

    // GEMM3: logits = u@g2 + bg2 ; softmax over 16 neighbors ;
    // then res_pre = sum_k attn*(v+pos) with attn+pos in registers
#pragma unroll
    for (int ct = 0; ct < 8; ct++) {
        float bb = bg2s[ct * 16 + lr];
        acc0[ct] = (f32x4){bb, bb, bb, bb};
        acc1[ct] = acc0[ct];
    }
    DO_GEMM(acc0, acc1, Wb)
    const float scale = 0.08838834764831845f; /* 1/sqrt(128) */
#pragma unroll
    for (int rt = 0; rt < 2; rt++) {
        const int rloc = rbase + rt * 16 + 4 * lg;
        const int j0 = jrow[rloc + 0], j1 = jrow[rloc + 1];
        const int j2 = jrow[rloc + 2], j3 = jrow[rloc + 3];
        const size_t vb0 = (size_t)((b << 13) + j0) * 128;
        const size_t vb1 = (size_t)((b << 13) + j1) * 128;
        const size_t vb2 = (size_t)((b << 13) + j2) * 128;
        const size_t vb3 = (size_t)((b << 13) + j3) * 128;
        f32x4* accR = rt ? acc1 : acc0;
        f32x4* posR = rt ? pos1 : pos0;
#pragma unroll
        for (int ct = 0; ct < 8; ct++) {
            const int c = ct * 16 + lr;
            f32x4 p = accR[ct];
            float l0 = p[0] * scale, l1 = p[1] * scale, l2 = p[2] * scale, l3 = p[3] * scale;
            float m = fmaxf(fmaxf(l0, l1), fmaxf(l2, l3));
            m = fmaxf(m, __shfl_xor(m, 16));
            m = fmaxf(m, __shfl_xor(m, 32));
            float e0 = __expf(l0 - m), e1 = __expf(l1 - m);
            float e2 = __expf(l2 - m), e3 = __expf(l3 - m);
            float s = (e0 + e1) + (e2 + e3);
            s += __shfl_xor(s, 16);
            s += __shfl_xor(s, 32);
            float inv = 1.0f / s;
            float a0 = e0 * inv, a1 = e1 * inv, a2 = e2 * inv, a3 = e3 * inv;
            size_t ob = (size_t)(R0 + rloc) * 128 + c;
            attn[ob + 0 * 128] = a0;
            attn[ob + 1 * 128] = a1;
            attn[ob + 2 * 128] = a2;
            attn[ob + 3 * 128] = a3;
            // value path: partial over this lane's 4 neighbors
            f32x4 pp = posR[ct];
            float r = a0 * (xv[vb0 + c] + pp[0])
                    + a1 * (xv[vb1 + c] + pp[1])
                    + a2 * (xv[vb2 + c] + pp[2])
                    + a3 * (xv[vb3 + c] + pp[3]);
            r += __shfl_xor(r, 16);
            r += __shfl_xor(r, 32);
            if (lg == 0)
                res_pre[(size_t)((R0 >> 4) + wv * 2 + rt) * 128 + c] = r;
        }
    }
}

// ---------------------------------------------------------------- res = res_pre@fc2 + b + features
__global__ __launch_bounds__(256, 1) void k6_kernel(const float* __restrict__ res_pre,
                                                    const float* __restrict__ w,
                                                    const float* __restrict__ bias,
                                                    const float* __restrict__ feats,
                                                    float* __restrict__ res_out) {
    __shared__ float At[128 * 65];
    __shared__ __align__(16) float Wt[128 * 64];
    const int t = threadIdx.x;
    const int base = blockIdx.x * 64;
#pragma unroll
    for (int e = 0; e < 32; e++) {
        int id = t + e * 256;
        int r = id >> 7, c = id & 127;
        At[c * 65 + r] = res_pre[(size_t)(base + r) * 128 + c];
    }
#pragma unroll
    for (int e = 0; e < 32; e++) { int id = t + e * 256; Wt[id] = w[id]; }
    __syncthreads();
    const int r0 = (t >> 4) * 4;
    const int c0 = (t & 15) * 4;
    float acc[4][4];
#pragma unroll
    for (int i = 0; i < 4; i++)
#pragma unroll
        for (int j = 0; j < 4; j++) acc[i][j] = bias[c0 + j];
#pragma unroll 4
    for (int kk = 0; kk < 128; ++kk) {
        float a0 = At[kk * 65 + r0 + 0];
        float a1 = At[kk * 65 + r0 + 1];
        float a2 = At[kk * 65 + r0 + 2];
        float a3 = At[kk * 65 + r0 + 3];
        const float4 w0 = *(const float4*)&Wt[kk * 64 + c0];
        float wj[4] = {w0.x, w0.y, w0.z, w0.w};
#pragma unroll
        for (int j = 0; j < 4; j++) {
            acc[0][j] += a0 * wj[j];
            acc[1][j] += a1 * wj[j];
            acc[2][j] += a2 * wj[j];
            acc[3][j] += a3 * wj[j];
        }
    }
#pragma unroll
    for (int i = 0; i < 4; i++)
#pragma unroll
        for (int j = 0; j < 4; j++)
            res_out[(size_t)(base + r0 + i) * 64 + c0 + j] =
                acc[i][j] + feats[(size_t)(base + r0 + i) * 64 + c0 + j];
}

extern "C" void kernel_launch(void* const* d_in, const int* in_sizes, int n_in,
                              void* d_out, int out_size, void* d_ws, size_t ws_size,
                              hipStream_t stream) {
    (void)in_sizes; (void)n_in; (void)out_size; (void)ws_size;
    const float* xyz   = (const float*)d_in[0];
    const float* feats = (const float*)d_in[2];
    const float* fc1_w = (const float*)d_in[3];
    const float* fc1_b = (const float*)d_in[4];
    const float* fc2_w = (const float*)d_in[5];
    const float* fc2_b = (const float*)d_in[6];
    const float* g1    = (const float*)d_in[7];
    const float* bg1   = (const float*)d_in[8];
    const float* g2    = (const float*)d_in[9];
    const float* bg2   = (const float*)d_in[10];
    const float* d1    = (const float*)d_in[11];
    const float* bd1   = (const float*)d_in[12];
    const float* d2    = (const float*)d_in[13];
    const float* bd2   = (const float*)d_in[14];
    const float* wq    = (const float*)d_in[15];
    const float* wk    = (const float*)d_in[16];
    const float* wv    = (const float*)d_in[17];

    int* idxw   = (int*)d_ws;
    float* xbuf = (float*)((char*)d_ws + (1 << 20));
    float* qbuf = xbuf + 2097152;
    float* kbuf = qbuf + 2097152;
    float* vbuf = kbuf + 2097152;
    float* rpre = vbuf + 2097152;
    __bf16* d2t = (__bf16*)(rpre + 2097152);
    __bf16* g1t = d2t + 16384;
    __bf16* g2t = g1t + 16384;

    float* res_out = (float*)d_out;
    float* attn    = res_out + 1048576;

    wprep_kernel<<<3, 256, 0, stream>>>(d2, g1, g2, d2t, g1t, g2t);
    knn_kernel<<<4096, 256, 0, stream>>>(xyz, idxw);
    gemm_x_kernel<<<256, 256, 0, stream>>>(feats, fc1_w, fc1_b, xbuf);
    gemm_qkv_kernel<<<dim3(256, 3), 256, 0, stream>>>(xbuf, wq, wk, wv, qbuf, kbuf, vbuf);
    k345_kernel<<<2048, 256, 0, stream>>>(xyz, idxw, qbuf, kbuf, vbuf, d1, bd1, bd2, bg1, bg2,
                                          d2t, g1t, g2t, attn, rpre);
    k6_kernel<<<256, 256, 0, stream>>>(rpre, fc2_w, fc2_b, feats, res_out);
}